// Round 7
// baseline (381.864 us; speedup 1.0000x reference)
//
#include <hip/hip_runtime.h>
#include <math.h>

#define BATCH 1024
#define TT    128
#define NBI   13
#define HH    128
#define T_INP 64
#define NG    512

typedef _Float16 half2v __attribute__((ext_vector_type(2)));

#if __has_builtin(__builtin_amdgcn_fdot2)
#define HAS_FDOT2 1
#else
#define HAS_FDOT2 0
#endif

__device__ __forceinline__ float dot2acc(float w, float h, float acc) {
#if HAS_FDOT2
    return __builtin_amdgcn_fdot2(__builtin_bit_cast(half2v, w),
                                  __builtin_bit_cast(half2v, h), acc, false);
#else
    half2v a = __builtin_bit_cast(half2v, w);
    half2v b = __builtin_bit_cast(half2v, h);
    return acc + (float)a[0] * (float)b[0] + (float)a[1] * (float)b[1];
#endif
}

__device__ __forceinline__ unsigned short f16b(float v) {
    return __builtin_bit_cast(unsigned short, (_Float16)v);
}
__device__ __forceinline__ float sigmoid_(float v) {
    return 1.0f / (1.0f + __expf(-v));
}
__device__ __forceinline__ float tanh_(float v) {
    float e = __expf(2.0f * v);
    return 1.0f - 2.0f / (e + 1.0f);
}

// In-loop opaque pin on 4 SCALAR floats (the only asm form the gfx950
// backend accepts). Placed inside the loop body, it makes the weight
// registers loop-carried through an opaque op: they cannot be
// rematerialized across the backedge, and with a 256-VGPR budget
// (launch_bounds min-waves=2) there is no pressure to spill them.
#define PIN4S(p) asm volatile("" : "+v"((p)[0]), "+v"((p)[1]), "+v"((p)[2]), "+v"((p)[3]))

// ---- ws layout (bytes) ----
#define WS_WHH   0            // ushort[512*128] teacher W_hh (f16)
#define WS_WHAT  131072       // ushort[512*128] folded Ŵ = W_hh + W_ih@W_out (f16)
#define WS_WIH   262144       // ushort[512*16]  W_ih padded 13->16 (f16)
#define WS_WOUT  278528       // ushort[13*128]  W_out (f16)
#define WS_BT    282624       // float[512] teacher bias = b_ih+b_hh
#define WS_BA    284672       // float[512] auto bias = b_ih+b_hh + W_ih@b_out

__global__ void fold_kernel(const float* __restrict__ W_ih,
                            const float* __restrict__ W_hh,
                            const float* __restrict__ b_ih,
                            const float* __restrict__ b_hh,
                            const float* __restrict__ W_out,
                            const float* __restrict__ b_out,
                            unsigned char* __restrict__ ws)
{
    const int j = blockIdx.x;   // gate row 0..511
    const int k = threadIdx.x;  // hidden col 0..127
    unsigned short* whh16  = (unsigned short*)(ws + WS_WHH);
    unsigned short* what16 = (unsigned short*)(ws + WS_WHAT);
    unsigned short* wih16  = (unsigned short*)(ws + WS_WIH);
    unsigned short* wout16 = (unsigned short*)(ws + WS_WOUT);
    float* bias_t = (float*)(ws + WS_BT);
    float* bias_a = (float*)(ws + WS_BA);

    float whh = W_hh[j * HH + k];
    float acc = whh;
#pragma unroll
    for (int m = 0; m < NBI; ++m)
        acc += W_ih[j * NBI + m] * W_out[m * HH + k];
    whh16[j * HH + k]  = f16b(whh);
    what16[j * HH + k] = f16b(acc);

    if (k < 16) wih16[j * 16 + k] = (k < NBI) ? f16b(W_ih[j * NBI + k]) : 0;
    if (k == 0) {
        float bt = b_ih[j] + b_hh[j];
        bias_t[j] = bt;
        float ba = bt;
#pragma unroll
        for (int m = 0; m < NBI; ++m) ba += W_ih[j * NBI + m] * b_out[m];
        bias_a[j] = ba;
    }
    if (j < NBI) wout16[j * HH + k] = f16b(W_out[j * HH + k]);
}

// min-waves-per-EU = 2 -> 256-VGPR budget: the ~110-reg working set fits
// with 2x slack, so the allocator has no incentive to remat/spill weights.
__global__ __launch_bounds__(512, 2)
void lstm_main(const float* __restrict__ x,
               const float* __restrict__ b_out,
               const unsigned char* __restrict__ ws,
               float* __restrict__ out)
{
    const int b = blockIdx.x;
    const int j = threadIdx.x;

    const unsigned short* whh16  = (const unsigned short*)(ws + WS_WHH);
    const unsigned short* what16 = (const unsigned short*)(ws + WS_WHAT);
    const unsigned short* wih16  = (const unsigned short*)(ws + WS_WIH);
    const unsigned short* wout16 = (const unsigned short*)(ws + WS_WOUT);
    const float* bias_t = (const float*)(ws + WS_BT);
    const float* bias_a = (const float*)(ws + WS_BA);

    __shared__ __align__(16) unsigned short h_s[HH];  // f16 hidden state
    __shared__ __align__(16) unsigned short x_s[16];  // f16 input (padded)
    __shared__ float gate_s[NG];

    // ---- register-resident weights: 64 VGPRs of f16-packed W_hh row ----
    float wreg[64];
    {
        const float4* wp = (const float4*)(whh16 + j * HH);
#pragma unroll
        for (int c2 = 0; c2 < 16; ++c2) {
            float4 v = wp[c2];
            wreg[4 * c2 + 0] = v.x; wreg[4 * c2 + 1] = v.y;
            wreg[4 * c2 + 2] = v.z; wreg[4 * c2 + 3] = v.w;
        }
    }
    float wif[8];
    {
        const float4* ip = (const float4*)(wih16 + j * 16);
        float4 v0 = ip[0], v1 = ip[1];
        wif[0] = v0.x; wif[1] = v0.y; wif[2] = v0.z; wif[3] = v0.w;
        wif[4] = v1.x; wif[5] = v1.y; wif[6] = v1.z; wif[7] = v1.w;
    }
    float bias_cur = bias_t[j];

    // projection role: 13 outputs x 8 partials = 104 threads
    const int part = j & 7;
    const int m    = (j < 104) ? (j >> 3) : 0;
    float wof[8];
    {
        const float4* op = (const float4*)(wout16 + m * HH + part * 16);
        float4 v0 = op[0], v1 = op[1];
        wof[0] = v0.x; wof[1] = v0.y; wof[2] = v0.z; wof[3] = v0.w;
        wof[4] = v1.x; wof[5] = v1.y; wof[6] = v1.z; wof[7] = v1.w;
    }
    float bo = 0.0f;
    if (part == 0 && j < 104) bo = b_out[m];

    const float* xb = x   + (size_t)b * TT * NBI;
    float*       ob = out + (size_t)b * TT * NBI;

    float c = 0.0f;
    if (j < HH) h_s[j] = 0;
    if (j < 16) {
        float v = (j < NBI) ? xb[j] : 0.0f;
        x_s[j] = f16b(v);
        if (j < NBI) ob[j] = v;   // out[:,0,:] = x[:,0,:]
    }
    __syncthreads();

    // =========== teacher loop: t = 0..64, input = x[:,t] ===========
    for (int t = 0; t <= T_INP; ++t) {
        // opaque pin: weights are loop-carried, cannot be remat'd/sunk
#pragma unroll
        for (int q = 0; q < 64; q += 4) PIN4S(&wreg[q]);
        PIN4S(&wif[0]); PIN4S(&wif[4]);
        PIN4S(&wof[0]); PIN4S(&wof[4]);

        float a0 = bias_cur, a1 = 0.f, a2 = 0.f, a3 = 0.f;
        const float4* h4 = (const float4*)h_s;
#pragma unroll
        for (int cb = 0; cb < 16; ++cb) {
            float4 hv = h4[cb];
            a0 = dot2acc(wreg[4 * cb + 0], hv.x, a0);
            a1 = dot2acc(wreg[4 * cb + 1], hv.y, a1);
            a2 = dot2acc(wreg[4 * cb + 2], hv.z, a2);
            a3 = dot2acc(wreg[4 * cb + 3], hv.w, a3);
        }
        {
            const float4* x4 = (const float4*)x_s;
            float4 xv0 = x4[0], xv1 = x4[1];
            a0 = dot2acc(wif[0], xv0.x, a0);
            a1 = dot2acc(wif[1], xv0.y, a1);
            a2 = dot2acc(wif[2], xv0.z, a2);
            a3 = dot2acc(wif[3], xv0.w, a3);
            a0 = dot2acc(wif[4], xv1.x, a0);
            a1 = dot2acc(wif[5], xv1.y, a1);
            a2 = dot2acc(wif[6], xv1.z, a2);
            a3 = dot2acc(wif[7], xv1.w, a3);
        }
        gate_s[j] = (a0 + a1) + (a2 + a3);

        // lagged projection: out[t] = W_out h^(t) + b_out (t>=1)
        float ps = 0.0f;
        if (t >= 1 && j < 104) {
            const float4* hp = ((const float4*)h_s) + part * 2;
            float4 p0 = hp[0], p1 = hp[1];
            ps = dot2acc(wof[0], p0.x, ps);
            ps = dot2acc(wof[1], p0.y, ps);
            ps = dot2acc(wof[2], p0.z, ps);
            ps = dot2acc(wof[3], p0.w, ps);
            ps = dot2acc(wof[4], p1.x, ps);
            ps = dot2acc(wof[5], p1.y, ps);
            ps = dot2acc(wof[6], p1.z, ps);
            ps = dot2acc(wof[7], p1.w, ps);
        }
        if (j < 128) {
            ps += __shfl_down(ps, 4, 64);
            ps += __shfl_down(ps, 2, 64);
            ps += __shfl_down(ps, 1, 64);
            if (t >= 1 && part == 0 && j < 104)
                ob[t * NBI + m] = ps + bo;
        }
        __syncthreads();  // gates ready; h_s/x_s readers done

        if (j < HH) {
            float ig = sigmoid_(gate_s[j]);
            float fg = sigmoid_(gate_s[j + 128]);
            float gg = tanh_(gate_s[j + 256]);
            float og = sigmoid_(gate_s[j + 384]);
            c = fg * c + ig * gg;
            h_s[j] = f16b(og * tanh_(c));
        } else if (j < 144) {
            if (t < T_INP) {
                int k = j - 128;
                float v = (k < NBI) ? xb[(t + 1) * NBI + k] : 0.0f;
                x_s[k] = f16b(v);
            }
        }
        __syncthreads();  // h_s ready for next step
    }

    // ---- switch to folded weights Ŵ = W_hh + W_ih@W_out, b̂ ----
    {
        const float4* ap = (const float4*)(what16 + j * HH);
#pragma unroll
        for (int c2 = 0; c2 < 16; ++c2) {
            float4 v = ap[c2];
            wreg[4 * c2 + 0] = v.x; wreg[4 * c2 + 1] = v.y;
            wreg[4 * c2 + 2] = v.z; wreg[4 * c2 + 3] = v.w;
        }
        bias_cur = bias_a[j];
    }

    // =========== auto loop: t = 65..126, gates = Ŵ·h + b̂ ===========
    for (int t = T_INP + 1; t < TT - 1; ++t) {
#pragma unroll
        for (int q = 0; q < 64; q += 4) PIN4S(&wreg[q]);
        PIN4S(&wof[0]); PIN4S(&wof[4]);

        float a0 = bias_cur, a1 = 0.f, a2 = 0.f, a3 = 0.f;
        const float4* h4 = (const float4*)h_s;
#pragma unroll
        for (int cb = 0; cb < 16; ++cb) {
            float4 hv = h4[cb];
            a0 = dot2acc(wreg[4 * cb + 0], hv.x, a0);
            a1 = dot2acc(wreg[4 * cb + 1], hv.y, a1);
            a2 = dot2acc(wreg[4 * cb + 2], hv.z, a2);
            a3 = dot2acc(wreg[4 * cb + 3], hv.w, a3);
        }
        gate_s[j] = (a0 + a1) + (a2 + a3);

        // lagged projection: out[t] = W_out h^(t) + b_out
        float ps = 0.0f;
        if (j < 104) {
            const float4* hp = ((const float4*)h_s) + part * 2;
            float4 p0 = hp[0], p1 = hp[1];
            ps = dot2acc(wof[0], p0.x, ps);
            ps = dot2acc(wof[1], p0.y, ps);
            ps = dot2acc(wof[2], p0.z, ps);
            ps = dot2acc(wof[3], p0.w, ps);
            ps = dot2acc(wof[4], p1.x, ps);
            ps = dot2acc(wof[5], p1.y, ps);
            ps = dot2acc(wof[6], p1.z, ps);
            ps = dot2acc(wof[7], p1.w, ps);
        }
        if (j < 128) {
            ps += __shfl_down(ps, 4, 64);
            ps += __shfl_down(ps, 2, 64);
            ps += __shfl_down(ps, 1, 64);
            if (part == 0 && j < 104)
                ob[t * NBI + m] = ps + bo;
        }
        __syncthreads();

        if (j < HH) {
            float ig = sigmoid_(gate_s[j]);
            float fg = sigmoid_(gate_s[j + 128]);
            float gg = tanh_(gate_s[j + 256]);
            float og = sigmoid_(gate_s[j + 384]);
            c = fg * c + ig * gg;
            h_s[j] = f16b(og * tanh_(c));
        }
        __syncthreads();
    }

    // ---- epilogue: out[127] = W_out h^(127) + b_out ----
    {
        float ps = 0.0f;
        if (j < 104) {
            const float4* hp = ((const float4*)h_s) + part * 2;
            float4 p0 = hp[0], p1 = hp[1];
            ps = dot2acc(wof[0], p0.x, ps);
            ps = dot2acc(wof[1], p0.y, ps);
            ps = dot2acc(wof[2], p0.z, ps);
            ps = dot2acc(wof[3], p0.w, ps);
            ps = dot2acc(wof[4], p1.x, ps);
            ps = dot2acc(wof[5], p1.y, ps);
            ps = dot2acc(wof[6], p1.z, ps);
            ps = dot2acc(wof[7], p1.w, ps);
        }
        if (j < 128) {
            ps += __shfl_down(ps, 4, 64);
            ps += __shfl_down(ps, 2, 64);
            ps += __shfl_down(ps, 1, 64);
            if (part == 0 && j < 104)
                ob[(TT - 1) * NBI + m] = ps + bo;
        }
    }
}

extern "C" void kernel_launch(void* const* d_in, const int* in_sizes, int n_in,
                              void* d_out, int out_size, void* d_ws, size_t ws_size,
                              hipStream_t stream)
{
    const float* x     = (const float*)d_in[0];
    const float* W_ih  = (const float*)d_in[1];
    const float* W_hh  = (const float*)d_in[2];
    const float* b_ih  = (const float*)d_in[3];
    const float* b_hh  = (const float*)d_in[4];
    const float* W_out = (const float*)d_in[5];
    const float* b_out = (const float*)d_in[6];
    float* out = (float*)d_out;
    unsigned char* ws = (unsigned char*)d_ws;

    fold_kernel<<<NG, HH, 0, stream>>>(W_ih, W_hh, b_ih, b_hh, W_out, b_out, ws);
    lstm_main<<<BATCH, 512, 0, stream>>>(x, b_out, ws, out);
}